// Round 3
// baseline (528.944 us; speedup 1.0000x reference)
//
#include <hip/hip_runtime.h>

// ReluTransformer backsubstitution, structure-exploiting version.
// w_lb / w_ub are [N+1, N+1] with: diag top-left NxN block, bias last column,
// last row = e_{N+1}. So the "GEMM" is elementwise scaling + one dot per row.
//
// R = 8192 rows, N = 4096 -> NCOLS = 4097 (odd stride: per-row float4
// alignment rotates mod 4, handled via 4 phase-shifted scale copies in ws).
//
// Structure: one wave per row, 4 waves/block, grid = NROWS/4.
// R3 = R2 with clang-native vector type for nontemporal builtins:
//   - __builtin_nontemporal_load/store reject HIP_vector_type (a class);
//     use ext_vector_type(4) float, layout-identical to float4.
//   - explicit 2-deep software pipeline on the HBM streams (lb/ub).
//   - nontemporal loads (lb/ub) + nontemporal stores (out): 537 MB of
//     read-once/write-once streams must not thrash the 32 MB L2; L2 is
//     reserved for the 262 KB scale arrays.

#define N_IN   4096
#define NCOLS  4097
#define NROWS  8192
#define PAD    4104   // multiple of 8, >= NCOLS

typedef float f32x4 __attribute__((ext_vector_type(4)));

// ws layout: 16 float arrays of PAD elements each:
//   index (s*4 + a)*PAD + i , a: 0=d_lb 1=d_ub 2=b_lb 3=b_ub
//   arr[s][a][i] = base_a[i + s]   (phase-shifted so float4 loads align)
__global__ void extract_scales(const float* __restrict__ w_lb,
                               const float* __restrict__ w_ub,
                               float* __restrict__ ws) {
    int j = blockIdx.x * blockDim.x + threadIdx.x;
    if (j >= NCOLS) return;
    size_t row = (size_t)j * NCOLS;
    float dlb = w_lb[row + j];       // diagonal entry (j==N_IN: w[N,N]=1, unused as diag)
    float dub = w_ub[row + j];
    float blb = w_lb[row + N_IN];    // last-column (bias) entry; blb[N]=w_lb[N,N]=1
    float bub = w_ub[row + N_IN];
#pragma unroll
    for (int s = 0; s < 4; ++s) {
        if (j >= s) {
            int i = j - s;
            ws[(size_t)(s * 4 + 0) * PAD + i] = dlb;
            ws[(size_t)(s * 4 + 1) * PAD + i] = dub;
            ws[(size_t)(s * 4 + 2) * PAD + i] = blb;
            ws[(size_t)(s * 4 + 3) * PAD + i] = bub;
        }
    }
}

__global__ __launch_bounds__(256) void backsub_rows(
        const float* __restrict__ lb, const float* __restrict__ ub,
        const float* __restrict__ ws, float* __restrict__ out) {
    const int wv   = threadIdx.x >> 6;          // wave id within block: 0..3
    const int lane = threadIdx.x & 63;
    const int r    = (blockIdx.x << 2) | wv;    // one row per wave
    // first column of row r such that (r*NCOLS + j0) % 4 == 0
    const int j0 = (4 - (r & 3)) & 3;
    const size_t row_off = (size_t)r * NCOLS;
    const float* lb_row  = lb + row_off;
    const float* ub_row  = ub + row_off;
    float* olb_row = out + row_off;
    float* oub_row = out + (size_t)NROWS * NCOLS + row_off;

    const int nv = (N_IN - j0) >> 2;               // full float4 chunks, cols < 4096
    const f32x4* lbv  = (const f32x4*)(lb_row + j0);
    const f32x4* ubv  = (const f32x4*)(ub_row + j0);
    f32x4*       olbv = (f32x4*)(olb_row + j0);
    f32x4*       oubv = (f32x4*)(oub_row + j0);
    const int s = j0;
    const f32x4* DL = (const f32x4*)(ws + (size_t)(s * 4 + 0) * PAD);
    const f32x4* DU = (const f32x4*)(ws + (size_t)(s * 4 + 1) * PAD);
    const f32x4* BL = (const f32x4*)(ws + (size_t)(s * 4 + 2) * PAD);
    const f32x4* BU = (const f32x4*)(ws + (size_t)(s * 4 + 3) * PAD);

    float acc_lb = 0.f, acc_ub = 0.f;

    // 2-deep pipeline over the HBM streams.
    int k = lane;
    f32x4 x = {0.f, 0.f, 0.f, 0.f}, y = {0.f, 0.f, 0.f, 0.f};
    if (k < nv) {
        x = __builtin_nontemporal_load(lbv + k);
        y = __builtin_nontemporal_load(ubv + k);
    }
    while (k < nv) {
        const int kn = k + 64;
        f32x4 xn = {0.f, 0.f, 0.f, 0.f}, yn = {0.f, 0.f, 0.f, 0.f};
        if (kn < nv) {
            xn = __builtin_nontemporal_load(lbv + kn);
            yn = __builtin_nontemporal_load(ubv + kn);
        }
        // scale loads: L2-resident, just-in-time
        f32x4 dl = DL[k];
        f32x4 du = DU[k];
        f32x4 bl = BL[k];
        f32x4 bu = BU[k];
        f32x4 ol, ou;
#define COMP(c) do { \
        float px = fmaxf(x[c], 0.f), mx = fminf(x[c], 0.f); \
        ol[c] = px * dl[c] + mx * du[c]; \
        acc_lb = fmaf(px, bl[c], fmaf(mx, bu[c], acc_lb)); \
        float py = fmaxf(y[c], 0.f), my = fminf(y[c], 0.f); \
        ou[c] = py * du[c] + my * dl[c]; \
        acc_ub = fmaf(py, bu[c], fmaf(my, bl[c], acc_ub)); \
    } while (0)
        COMP(0); COMP(1); COMP(2); COMP(3);
#undef COMP
        __builtin_nontemporal_store(ol, olbv + k);
        __builtin_nontemporal_store(ou, oubv + k);
        x = xn; y = yn; k = kn;
    }

    // scalar head [0, j0) and tail [j0 + 4*nv, NCOLS): at most 5 lanes active
    {
        const int tail = j0 + 4 * nv;
        const int nsc  = j0 + (NCOLS - tail);
        if (lane < nsc) {
            const int j = (lane < j0) ? lane : (tail + lane - j0);
            const float* DL0 = ws + 0 * PAD;   // phase-0 = unshifted arrays
            const float* DU0 = ws + 1 * PAD;
            const float* BL0 = ws + 2 * PAD;
            const float* BU0 = ws + 3 * PAD;
            float dl = DL0[j], du = DU0[j], bl = BL0[j], bu = BU0[j];
            float xs = lb_row[j], ys = ub_row[j];
            float px = fmaxf(xs, 0.f), mx = fminf(xs, 0.f);
            if (j < N_IN) olb_row[j] = px * dl + mx * du;
            acc_lb = fmaf(px, bl, fmaf(mx, bu, acc_lb));
            float py = fmaxf(ys, 0.f), my = fminf(ys, 0.f);
            if (j < N_IN) oub_row[j] = py * du + my * dl;
            acc_ub = fmaf(py, bu, fmaf(my, bl, acc_ub));
        }
    }

    // wave-local reduction only: no LDS, no __syncthreads
    for (int o = 32; o > 0; o >>= 1) {
        acc_lb += __shfl_down(acc_lb, o, 64);
        acc_ub += __shfl_down(acc_ub, o, 64);
    }
    if (lane == 0) {
        olb_row[N_IN] = acc_lb;
        oub_row[N_IN] = acc_ub;
    }
}

extern "C" void kernel_launch(void* const* d_in, const int* in_sizes, int n_in,
                              void* d_out, int out_size, void* d_ws, size_t ws_size,
                              hipStream_t stream) {
    const float* lb   = (const float*)d_in[0];
    const float* ub   = (const float*)d_in[1];
    const float* w_lb = (const float*)d_in[2];
    const float* w_ub = (const float*)d_in[3];
    float* out = (float*)d_out;
    float* ws  = (float*)d_ws;   // needs 16*PAD*4 = 262,656 bytes

    extract_scales<<<(NCOLS + 255) / 256, 256, 0, stream>>>(w_lb, w_ub, ws);
    backsub_rows<<<NROWS / 4, 256, 0, stream>>>(lb, ub, ws, out);
}

// Round 4
// 511.270 us; speedup vs baseline: 1.0346x; 1.0346x over previous
//
#include <hip/hip_runtime.h>

// ReluTransformer backsubstitution, structure-exploiting version.
// w_lb / w_ub are [N+1, N+1] with: diag top-left NxN block, bias last column,
// last row = e_{N+1}. So the "GEMM" is elementwise scaling + one dot per row.
//
// R = 8192 rows, N = 4096 -> NCOLS = 4097 (odd stride: per-row float4
// alignment rotates mod 4, handled via 4 phase-shifted scale copies in ws).
//
// R4: revert R1/R3 deltas (wave-per-row, nontemporal, sw pipeline — all
// regressed). Back to R0's block-per-row structure with ONE change:
//   TWO ROWS PER BLOCK (r and r+4, which share the alignment phase j0).
//   One dl/du/bl/bu load now feeds both rows:
//     - scale L2 traffic halves: 537 MB -> 268 MB
//     - loop loads per 2-row unit: 12 -> 8 (-33% load instructions)
//   HBM traffic unchanged (compulsory 537 MB).

#define N_IN   4096
#define NCOLS  4097
#define NROWS  8192
#define PAD    4104   // multiple of 8, >= NCOLS

// ws layout: 16 float arrays of PAD elements each:
//   index (s*4 + a)*PAD + i , a: 0=d_lb 1=d_ub 2=b_lb 3=b_ub
//   arr[s][a][i] = base_a[i + s]   (phase-shifted so float4 loads align)
__global__ void extract_scales(const float* __restrict__ w_lb,
                               const float* __restrict__ w_ub,
                               float* __restrict__ ws) {
    int j = blockIdx.x * blockDim.x + threadIdx.x;
    if (j >= NCOLS) return;
    size_t row = (size_t)j * NCOLS;
    float dlb = w_lb[row + j];       // diagonal entry (j==N_IN: w[N,N]=1, unused as diag)
    float dub = w_ub[row + j];
    float blb = w_lb[row + N_IN];    // last-column (bias) entry; blb[N]=w_lb[N,N]=1
    float bub = w_ub[row + N_IN];
#pragma unroll
    for (int s = 0; s < 4; ++s) {
        if (j >= s) {
            int i = j - s;
            ws[(size_t)(s * 4 + 0) * PAD + i] = dlb;
            ws[(size_t)(s * 4 + 1) * PAD + i] = dub;
            ws[(size_t)(s * 4 + 2) * PAD + i] = blb;
            ws[(size_t)(s * 4 + 3) * PAD + i] = bub;
        }
    }
}

__global__ __launch_bounds__(256) void backsub_rows(
        const float* __restrict__ lb, const float* __restrict__ ub,
        const float* __restrict__ ws, float* __restrict__ out) {
    const int tid = threadIdx.x;
    const int b   = blockIdx.x;
    // rows rA and rB = rA+4 share (r & 3), hence the same phase j0
    const int rA  = ((b >> 2) << 3) | (b & 3);
    const int j0  = (4 - (rA & 3)) & 3;   // (rA*NCOLS + j0) % 4 == 0

    const size_t offA = (size_t)rA * NCOLS;
    const size_t offB = offA + (size_t)4 * NCOLS;   // row rA+4
    const float* lbA = lb + offA;
    const float* ubA = ub + offA;
    const float* lbB = lb + offB;
    const float* ubB = ub + offB;
    float* olbA = out + offA;
    float* oubA = out + (size_t)NROWS * NCOLS + offA;
    float* olbB = out + offB;
    float* oubB = out + (size_t)NROWS * NCOLS + offB;

    const int nv = (N_IN - j0) >> 2;               // full float4 chunks, cols < 4096
    const float4* lbvA  = (const float4*)(lbA + j0);
    const float4* ubvA  = (const float4*)(ubA + j0);
    const float4* lbvB  = (const float4*)(lbB + j0);
    const float4* ubvB  = (const float4*)(ubB + j0);
    float4*       olbvA = (float4*)(olbA + j0);
    float4*       oubvA = (float4*)(oubA + j0);
    float4*       olbvB = (float4*)(olbB + j0);
    float4*       oubvB = (float4*)(oubB + j0);
    const int s = j0;
    const float4* DL = (const float4*)(ws + (size_t)(s * 4 + 0) * PAD);
    const float4* DU = (const float4*)(ws + (size_t)(s * 4 + 1) * PAD);
    const float4* BL = (const float4*)(ws + (size_t)(s * 4 + 2) * PAD);
    const float4* BU = (const float4*)(ws + (size_t)(s * 4 + 3) * PAD);

    float aLA = 0.f, aUA = 0.f, aLB = 0.f, aUB = 0.f;

    for (int k = tid; k < nv; k += 256) {
        float4 dl = DL[k];
        float4 du = DU[k];
        float4 bl = BL[k];
        float4 bu = BU[k];
        float4 xA = lbvA[k];
        float4 yA = ubvA[k];
        float4 xB = lbvB[k];
        float4 yB = ubvB[k];
        float4 olA, ouA, olB, ouB;
#define COMP(c) do { \
        float px = fmaxf(xA.c, 0.f), mx = fminf(xA.c, 0.f); \
        olA.c = px * dl.c + mx * du.c; \
        aLA = fmaf(px, bl.c, fmaf(mx, bu.c, aLA)); \
        float py = fmaxf(yA.c, 0.f), my = fminf(yA.c, 0.f); \
        ouA.c = py * du.c + my * dl.c; \
        aUA = fmaf(py, bu.c, fmaf(my, bl.c, aUA)); \
        px = fmaxf(xB.c, 0.f); mx = fminf(xB.c, 0.f); \
        olB.c = px * dl.c + mx * du.c; \
        aLB = fmaf(px, bl.c, fmaf(mx, bu.c, aLB)); \
        py = fmaxf(yB.c, 0.f); my = fminf(yB.c, 0.f); \
        ouB.c = py * du.c + my * dl.c; \
        aUB = fmaf(py, bu.c, fmaf(my, bl.c, aUB)); \
    } while (0)
        COMP(x); COMP(y); COMP(z); COMP(w);
#undef COMP
        olbvA[k] = olA;
        oubvA[k] = ouA;
        olbvB[k] = olB;
        oubvB[k] = ouB;
    }

    // scalar head [0, j0) and tail [j0 + 4*nv, NCOLS): at most 5 lanes active,
    // each handles column j for BOTH rows (same j0 phase).
    {
        const int tail = j0 + 4 * nv;
        const int nsc  = j0 + (NCOLS - tail);
        if (tid < nsc) {
            const int j = (tid < j0) ? tid : (tail + tid - j0);
            const float* DL0 = ws + 0 * PAD;   // phase-0 = unshifted arrays
            const float* DU0 = ws + 1 * PAD;
            const float* BL0 = ws + 2 * PAD;
            const float* BU0 = ws + 3 * PAD;
            float dl = DL0[j], du = DU0[j], bl = BL0[j], bu = BU0[j];
            {   // row A
                float x = lbA[j], y = ubA[j];
                float px = fmaxf(x, 0.f), mx = fminf(x, 0.f);
                if (j < N_IN) olbA[j] = px * dl + mx * du;
                aLA = fmaf(px, bl, fmaf(mx, bu, aLA));
                float py = fmaxf(y, 0.f), my = fminf(y, 0.f);
                if (j < N_IN) oubA[j] = py * du + my * dl;
                aUA = fmaf(py, bu, fmaf(my, bl, aUA));
            }
            {   // row B
                float x = lbB[j], y = ubB[j];
                float px = fmaxf(x, 0.f), mx = fminf(x, 0.f);
                if (j < N_IN) olbB[j] = px * dl + mx * du;
                aLB = fmaf(px, bl, fmaf(mx, bu, aLB));
                float py = fmaxf(y, 0.f), my = fminf(y, 0.f);
                if (j < N_IN) oubB[j] = py * du + my * dl;
                aUB = fmaf(py, bu, fmaf(my, bl, aUB));
            }
        }
    }

    // block reduction: wave shuffle (width 64) then LDS across 4 waves
    for (int o = 32; o > 0; o >>= 1) {
        aLA += __shfl_down(aLA, o, 64);
        aUA += __shfl_down(aUA, o, 64);
        aLB += __shfl_down(aLB, o, 64);
        aUB += __shfl_down(aUB, o, 64);
    }
    __shared__ float red[4][4];
    const int wave = tid >> 6;
    if ((tid & 63) == 0) {
        red[wave][0] = aLA;
        red[wave][1] = aUA;
        red[wave][2] = aLB;
        red[wave][3] = aUB;
    }
    __syncthreads();
    if (tid == 0) {
        olbA[N_IN] = (red[0][0] + red[1][0]) + (red[2][0] + red[3][0]);
        oubA[N_IN] = (red[0][1] + red[1][1]) + (red[2][1] + red[3][1]);
        olbB[N_IN] = (red[0][2] + red[1][2]) + (red[2][2] + red[3][2]);
        oubB[N_IN] = (red[0][3] + red[1][3]) + (red[2][3] + red[3][3]);
    }
}

extern "C" void kernel_launch(void* const* d_in, const int* in_sizes, int n_in,
                              void* d_out, int out_size, void* d_ws, size_t ws_size,
                              hipStream_t stream) {
    const float* lb   = (const float*)d_in[0];
    const float* ub   = (const float*)d_in[1];
    const float* w_lb = (const float*)d_in[2];
    const float* w_ub = (const float*)d_in[3];
    float* out = (float*)d_out;
    float* ws  = (float*)d_ws;   // needs 16*PAD*4 = 262,656 bytes

    extract_scales<<<(NCOLS + 255) / 256, 256, 0, stream>>>(w_lb, w_ub, ws);
    backsub_rows<<<NROWS / 2, 256, 0, stream>>>(lb, ub, ws, out);
}